// Round 1
// baseline (132.875 us; speedup 1.0000x reference)
//
#include <hip/hip_runtime.h>
#include <stdint.h>

// VarifoldKernel: out[b] = sum_{n,m} w1[b,n]*w2[b,m]*exp(-2*||p1-p2||^2)*exp(-f1.f2/2)
// Rewritten as 2^( dot(U1[n],U2[m]) + la1[n] + la2[m] ) with
//   U1 = [2*pos1, feat1] (fp16), U2 = [2*L*pos2, -0.5*L*feat2] (fp16), L = log2(e)
//   la = log2(w) - 2*L*|pos|^2   (log-space rank-1 terms: overflow-safe)
// K = 3+64 = 67, zero-padded to 96. fp16 MFMA (16x16x32), fp32 accumulate.

typedef _Float16 f16;
typedef _Float16 v8h __attribute__((ext_vector_type(8)));
typedef _Float16 h2  __attribute__((ext_vector_type(2)));
typedef float    v4f __attribute__((ext_vector_type(4)));

#define L2E 1.4426950408889634f
#define BN 4096   // rows per batch per side
#define KP 96     // padded K
#define LDK 104   // LDS row stride in halfs (208 B = 52 words -> 2-way bank aliasing, free)

// ---------------- prep: pack fp32 inputs -> fp16 U matrices + log-space row terms ----
__global__ __launch_bounds__(256) void prep_kernel(
    const float* __restrict__ pos1, const float* __restrict__ feat1, const float* __restrict__ w1,
    const float* __restrict__ pos2, const float* __restrict__ feat2, const float* __restrict__ w2,
    f16* __restrict__ U1, f16* __restrict__ U2,
    float* __restrict__ la1, float* __restrict__ la2)
{
    int tid = blockIdx.x * blockDim.x + threadIdx.x;   // 0..32767
    int side = tid >> 14;                              // 0: side1, 1: side2
    int idx  = tid & 16383;                            // b*4096 + row

    const float* pos  = side ? pos2  : pos1;
    const float* feat = side ? feat2 : feat1;
    const float* w    = side ? w2    : w1;
    f16*   U  = side ? U2  : U1;
    float* la = side ? la2 : la1;
    float ps = side ? 2.0f * L2E : 2.0f;     // pos scale (log2e folded into side 2)
    float fs = side ? -0.5f * L2E : 1.0f;    // feat scale

    float p0 = pos[idx*3+0], p1 = pos[idx*3+1], p2 = pos[idx*3+2];
    float sq = p0*p0 + p1*p1 + p2*p2;
    float wv = w[idx];
    la[idx] = __builtin_amdgcn_logf(wv) - 2.0f * L2E * sq;   // v_log_f32 = log2

    h2* Urow = (h2*)(U + (long)idx * KP);
    Urow[0] = h2{(f16)(p0*ps), (f16)(p1*ps)};
    Urow[1] = h2{(f16)(p2*ps), (f16)0.0f};   // slot 3 is zero pad
    const float* fr = feat + (long)idx * 64;
    #pragma unroll
    for (int f = 0; f < 32; ++f)
        Urow[2+f] = h2{(f16)(fr[2*f]*fs), (f16)(fr[2*f+1]*fs)};
    #pragma unroll
    for (int z = 0; z < 14; ++z)             // halfs 68..95 zero
        Urow[34+z] = h2{(f16)0.0f, (f16)0.0f};
}

// ---------------- main: 128x128 tile, full-K in LDS, fused exp + reduce -------------
__global__ __launch_bounds__(256, 3) void varifold_kernel(
    const f16* __restrict__ U1, const f16* __restrict__ U2,
    const float* __restrict__ la1, const float* __restrict__ la2,
    float* __restrict__ out)
{
    __shared__ __align__(16) f16 sA[128 * LDK];   // 26624 B
    __shared__ __align__(16) f16 sB[128 * LDK];   // 26624 B
    __shared__ __align__(16) float s1[128];       // la1 tile
    __shared__ __align__(16) float s2[128];       // la2 tile
    // total 54272 B -> 3 blocks/CU

    int mb = blockIdx.x, nb = blockIdx.y, b = blockIdx.z;
    int tid = threadIdx.x;

    // --- stage A/B tiles (each 128 rows x 96 halfs, globally contiguous) ---
    const float4* gA = (const float4*)(U1 + ((long)b*BN + nb*128) * KP);  // 1536 float4
    const float4* gB = (const float4*)(U2 + ((long)b*BN + mb*128) * KP);
    #pragma unroll
    for (int it = 0; it < 12; ++it) {
        int i = it * 256 + tid;                  // 0..3071, wave-uniform branch below
        int src = (i < 1536) ? i : i - 1536;
        int row = src / 12, c = src - row * 12;  // c: 16B chunk within row
        float4 v = (i < 1536) ? gA[src] : gB[src];
        f16* base = (i < 1536) ? sA : sB;
        *((float4*)(base + row * LDK) + c) = v;
    }
    if (tid < 128)      s1[tid]       = la1[(long)b*BN + nb*128 + tid];
    else                s2[tid - 128] = la2[(long)b*BN + mb*128 + (tid - 128)];
    __syncthreads();

    // --- MFMA: 2x2 waves, each 4x4 tiles of 16x16 ---
    int wave = tid >> 6, lane = tid & 63;
    int wr = wave >> 1, wc = wave & 1;
    int l15 = lane & 15, quad = lane >> 4;
    int ko = quad * 8;

    v4f acc[4][4];
    #pragma unroll
    for (int i = 0; i < 4; ++i)
        #pragma unroll
        for (int j = 0; j < 4; ++j)
            acc[i][j] = v4f{0.f, 0.f, 0.f, 0.f};

    const f16* Abase = sA + (wr*64 + l15) * LDK + ko;
    const f16* Bbase = sB + (wc*64 + l15) * LDK + ko;
    #pragma unroll
    for (int kk = 0; kk < KP; kk += 32) {
        v8h af[4], bf[4];
        #pragma unroll
        for (int i = 0; i < 4; ++i) af[i] = *(const v8h*)(Abase + i*16*LDK + kk);
        #pragma unroll
        for (int j = 0; j < 4; ++j) bf[j] = *(const v8h*)(Bbase + j*16*LDK + kk);
        #pragma unroll
        for (int i = 0; i < 4; ++i)
            #pragma unroll
            for (int j = 0; j < 4; ++j)
                acc[i][j] = __builtin_amdgcn_mfma_f32_16x16x32_f16(af[i], bf[j], acc[i][j], 0, 0, 0);
    }

    // --- epilogue: term = 2^(d + la1[n] + la2[m]); C/D layout col=lane&15, row=quad*4+r
    float psum = 0.f;
    #pragma unroll
    for (int i = 0; i < 4; ++i) {
        float4 l1 = *(const float4*)&s1[wr*64 + i*16 + quad*4];
        #pragma unroll
        for (int j = 0; j < 4; ++j) {
            float l2 = s2[wc*64 + j*16 + l15];
            v4f d = acc[i][j];
            psum += __builtin_amdgcn_exp2f(d[0] + l1.x + l2);
            psum += __builtin_amdgcn_exp2f(d[1] + l1.y + l2);
            psum += __builtin_amdgcn_exp2f(d[2] + l1.z + l2);
            psum += __builtin_amdgcn_exp2f(d[3] + l1.w + l2);
        }
    }

    // --- reduce: wave shuffle -> LDS -> one atomic per block ---
    #pragma unroll
    for (int off = 32; off > 0; off >>= 1) psum += __shfl_down(psum, off);

    __syncthreads();                    // all s1/s2 reads done; safe to reuse
    float* sred = (float*)s1;
    if (lane == 0) sred[wave] = psum;
    __syncthreads();
    if (tid == 0) atomicAdd(out + b, sred[0] + sred[1] + sred[2] + sred[3]);
}

extern "C" void kernel_launch(void* const* d_in, const int* in_sizes, int n_in,
                              void* d_out, int out_size, void* d_ws, size_t ws_size,
                              hipStream_t stream) {
    const float* pos1  = (const float*)d_in[0];
    const float* feat1 = (const float*)d_in[1];
    const float* w1    = (const float*)d_in[2];
    const float* pos2  = (const float*)d_in[3];
    const float* feat2 = (const float*)d_in[4];
    const float* w2    = (const float*)d_in[5];
    float* out = (float*)d_out;

    // workspace layout (needs 6,422,528 B)
    char* ws = (char*)d_ws;
    f16*   U1  = (f16*)(ws);                         // 4*4096*96*2 = 3,145,728
    f16*   U2  = (f16*)(ws + 3145728);               // 3,145,728
    float* la1 = (float*)(ws + 6291456);             // 65,536
    float* la2 = (float*)(ws + 6291456 + 65536);     // 65,536

    hipMemsetAsync(d_out, 0, out_size * sizeof(float), stream);
    prep_kernel<<<128, 256, 0, stream>>>(pos1, feat1, w1, pos2, feat2, w2, U1, U2, la1, la2);
    dim3 grid(32, 32, 4);  // (mb, nb, b)
    varifold_kernel<<<grid, 256, 0, stream>>>(U1, U2, la1, la2, out);
}

// Round 2
// 94.042 us; speedup vs baseline: 1.4129x; 1.4129x over previous
//
#include <hip/hip_runtime.h>
#include <stdint.h>

// VarifoldKernel: out[b] = sum_{n,m} w1[b,n]*w2[b,m]*exp(-2*||p1-p2||^2)*exp(-f1.f2/2)
// Log-space: term = 2^( dot(U1[n],U2[m]) + la1[n] + la2[m] ),
//   U1 = [2*pos1, feat1] fp16, U2 = [2*L*pos2, -0.5*L*feat2] fp16, L = log2(e)
//   la = log2(w) - 2*L*|pos|^2
// K = 67 padded to 96. fp16 MFMA 16x16x32, fp32 accumulate.
// R2: global_load_lds staging (no VGPR round-trip), 128x256 tile / 512 thr
//     (4 waves/SIMD), partial-sum buffer + reduce kernel (no atomics),
//     coalesced prep.

typedef _Float16 f16;
typedef _Float16 v8h __attribute__((ext_vector_type(8)));
typedef _Float16 h4  __attribute__((ext_vector_type(4)));
typedef float    v4f __attribute__((ext_vector_type(4)));

#define L2E 1.4426950408889634f
#define BN 4096
#define KP 96    // padded K (halfs); row = 192 B; stride 48 words -> uniform 8/bank on b128

__device__ __forceinline__ void load_lds16(const void* g, void* s) {
    __builtin_amdgcn_global_load_lds((const __attribute__((address_space(1))) void*)g,
                                     (__attribute__((address_space(3))) void*)s,
                                     16, 0, 0);
}

// ---------------- prep: fp32 -> fp16 U matrices + log-space row terms ----------------
// 16 threads per row; feat via float4 (coalesced 1KB per wave), stores as 8B half4.
__global__ __launch_bounds__(256) void prep_kernel(
    const float* __restrict__ pos1, const float* __restrict__ feat1, const float* __restrict__ w1,
    const float* __restrict__ pos2, const float* __restrict__ feat2, const float* __restrict__ w2,
    f16* __restrict__ U1, f16* __restrict__ U2,
    float* __restrict__ la1, float* __restrict__ la2)
{
    int tid  = threadIdx.x;
    int ridx = blockIdx.x * 16 + (tid >> 4);   // 0..32767
    int c    = tid & 15;
    int side = ridx >> 14;                     // 0: side1, 1: side2
    int idx  = ridx & 16383;                   // b*4096 + row

    const float* feat = side ? feat2 : feat1;
    f16* U   = side ? U2 : U1;
    float fs = side ? -0.5f * L2E : 1.0f;

    float4 v = ((const float4*)feat)[idx * 16 + c];
    *(h4*)(U + (long)idx * KP + 4 + c * 4) =
        h4{(f16)(v.x * fs), (f16)(v.y * fs), (f16)(v.z * fs), (f16)(v.w * fs)};

    if (c == 0) {
        const float* pos = side ? pos2 : pos1;
        const float* w   = side ? w2   : w1;
        float* la = side ? la2 : la1;
        float ps  = side ? 2.0f * L2E : 2.0f;
        float p0 = pos[idx*3+0], p1 = pos[idx*3+1], p2 = pos[idx*3+2];
        la[idx] = __builtin_amdgcn_logf(w[idx]) - 2.0f * L2E * (p0*p0 + p1*p1 + p2*p2);
        *(h4*)(U + (long)idx * KP) = h4{(f16)(p0*ps), (f16)(p1*ps), (f16)(p2*ps), (f16)0.0f};
    } else if (c <= 7) {
        *(h4*)(U + (long)idx * KP + 68 + (c - 1) * 4) =
            h4{(f16)0.0f, (f16)0.0f, (f16)0.0f, (f16)0.0f};
    }
}

// ---------------- main: 128x256 tile, full-K LDS, fused exp2 + block reduce ---------
__global__ __launch_bounds__(512, 4) void varifold_kernel(
    const f16* __restrict__ U1, const f16* __restrict__ U2,
    const float* __restrict__ la1, const float* __restrict__ la2,
    float* __restrict__ pw)
{
    __shared__ __align__(1024) f16 sAB[(128 + 256) * KP];  // 73728 B, unpadded (global_load_lds)
    __shared__ float s1[128];
    __shared__ float s2[256];
    __shared__ float sred[8];
    // total ~75.3 KB -> 2 blocks/CU, 16 waves/CU

    f16* sA = sAB;
    f16* sB = sAB + 128 * KP;

    int mb = blockIdx.x, nb = blockIdx.y, b = blockIdx.z;
    int tid = threadIdx.x;
    int wave = tid >> 6, lane = tid & 63;

    const char* gA = (const char*)(U1 + ((long)b*BN + nb*128) * KP);  // 24576 B contiguous
    const char* gB = (const char*)(U2 + ((long)b*BN + mb*256) * KP);  // 49152 B contiguous

    // 72 chunks of 1KB (24 A + 48 B); wave w stages chunks [9w, 9w+9)
    #pragma unroll
    for (int i = 0; i < 9; ++i) {
        int c = wave * 9 + i;                               // wave-uniform
        const char* src = (c < 24) ? (gA + c * 1024 + lane * 16)
                                   : (gB + (c - 24) * 1024 + lane * 16);
        load_lds16(src, (char*)sAB + c * 1024);
    }
    if (tid < 128)      s1[tid]       = la1[(long)b*BN + nb*128 + tid];
    else if (tid < 384) s2[tid - 128] = la2[(long)b*BN + mb*256 + (tid - 128)];
    __syncthreads();

    // --- MFMA: waves as 2 (A-rows) x 4 (B-cols), each 4x4 tiles of 16x16 ---
    int wr = wave >> 2, wc = wave & 3;
    int l15 = lane & 15, quad = lane >> 4;
    int ko = quad * 8;

    v4f acc[4][4];
    #pragma unroll
    for (int i = 0; i < 4; ++i)
        #pragma unroll
        for (int j = 0; j < 4; ++j)
            acc[i][j] = v4f{0.f, 0.f, 0.f, 0.f};

    const f16* Ab = sA + (wr*64 + l15) * KP + ko;
    const f16* Bb = sB + (wc*64 + l15) * KP + ko;
    #pragma unroll
    for (int kk = 0; kk < KP; kk += 32) {
        v8h af[4], bf[4];
        #pragma unroll
        for (int i = 0; i < 4; ++i) af[i] = *(const v8h*)(Ab + i*16*KP + kk);
        #pragma unroll
        for (int j = 0; j < 4; ++j) bf[j] = *(const v8h*)(Bb + j*16*KP + kk);
        #pragma unroll
        for (int i = 0; i < 4; ++i)
            #pragma unroll
            for (int j = 0; j < 4; ++j)
                acc[i][j] = __builtin_amdgcn_mfma_f32_16x16x32_f16(af[i], bf[j], acc[i][j], 0, 0, 0);
    }

    // --- epilogue: term = 2^(d + la1 + la2); C/D: col=lane&15, row=quad*4+reg ---
    float psum = 0.f;
    #pragma unroll
    for (int i = 0; i < 4; ++i) {
        float4 l1 = *(const float4*)&s1[wr*64 + i*16 + quad*4];
        #pragma unroll
        for (int j = 0; j < 4; ++j) {
            float l2 = s2[wc*64 + j*16 + l15];
            v4f d = acc[i][j];
            psum += __builtin_amdgcn_exp2f(d[0] + l1.x + l2);
            psum += __builtin_amdgcn_exp2f(d[1] + l1.y + l2);
            psum += __builtin_amdgcn_exp2f(d[2] + l1.z + l2);
            psum += __builtin_amdgcn_exp2f(d[3] + l1.w + l2);
        }
    }

    // --- reduce: wave shuffle -> LDS -> one plain store per block (no atomics) ---
    #pragma unroll
    for (int off = 32; off > 0; off >>= 1) psum += __shfl_down(psum, off);
    if (lane == 0) sred[wave] = psum;
    __syncthreads();
    if (tid == 0) {
        float s = 0.f;
        #pragma unroll
        for (int w = 0; w < 8; ++w) s += sred[w];
        pw[(long)b * 512 + nb * 16 + mb] = s;
    }
}

// ---------------- final: reduce 512 partials per batch -> out[b] --------------------
__global__ __launch_bounds__(256) void reduce_kernel(
    const float* __restrict__ pw, float* __restrict__ out)
{
    __shared__ float sred[4];
    int b = blockIdx.x, tid = threadIdx.x;
    float v = pw[(long)b * 512 + tid] + pw[(long)b * 512 + 256 + tid];
    #pragma unroll
    for (int off = 32; off > 0; off >>= 1) v += __shfl_down(v, off);
    if ((tid & 63) == 0) sred[tid >> 6] = v;
    __syncthreads();
    if (tid == 0) out[b] = sred[0] + sred[1] + sred[2] + sred[3];
}

extern "C" void kernel_launch(void* const* d_in, const int* in_sizes, int n_in,
                              void* d_out, int out_size, void* d_ws, size_t ws_size,
                              hipStream_t stream) {
    const float* pos1  = (const float*)d_in[0];
    const float* feat1 = (const float*)d_in[1];
    const float* w1    = (const float*)d_in[2];
    const float* pos2  = (const float*)d_in[3];
    const float* feat2 = (const float*)d_in[4];
    const float* w2    = (const float*)d_in[5];
    float* out = (float*)d_out;

    // workspace layout (6,430,720 B)
    char* ws = (char*)d_ws;
    f16*   U1  = (f16*)(ws);                          // 3,145,728
    f16*   U2  = (f16*)(ws + 3145728);                // 3,145,728
    float* la1 = (float*)(ws + 6291456);              // 65,536
    float* la2 = (float*)(ws + 6291456 + 65536);      // 65,536
    float* pw  = (float*)(ws + 6291456 + 131072);     // 2048*4 = 8,192

    prep_kernel<<<2048, 256, 0, stream>>>(pos1, feat1, w1, pos2, feat2, w2, U1, U2, la1, la2);
    dim3 grid(16, 32, 4);  // (mb, nb, b)
    varifold_kernel<<<grid, 512, 0, stream>>>(U1, U2, la1, la2, pw);
    reduce_kernel<<<4, 256, 0, stream>>>(pw, out);
}

// Round 3
// 92.948 us; speedup vs baseline: 1.4296x; 1.0118x over previous
//
#include <hip/hip_runtime.h>
#include <stdint.h>

// VarifoldKernel: out[b] = sum_{n,m} w1[b,n]*w2[b,m]*exp(-2*||p1-p2||^2)*exp(-f1.f2/2)
// Log-space: term = 2^( dot(U1[n],U2[m]) + la1[n] + la2[m] ),
//   U1 = [2*pos1, feat1] fp16, U2 = [2*L*pos2, -0.5*L*feat2] fp16, L = log2(e)
//   la = log2(w) - 2*L*|pos|^2
// K = 67 padded to 96. fp16 MFMA 16x16x32, fp32 accumulate.
// R3: NO LDS, NO barriers. Wave-persistent B-stripe in registers (64 cols,
//     48 VGPRs), A fragments streamed global->VGPR with 1-tile prefetch.
//     4 blocks/CU (4 waves/SIMD), grid ordered stripe-fastest for A locality.

typedef _Float16 f16;
typedef _Float16 v8h __attribute__((ext_vector_type(8)));
typedef _Float16 h4  __attribute__((ext_vector_type(4)));
typedef float    v4f __attribute__((ext_vector_type(4)));

#define L2E 1.4426950408889634f
#define BN 4096
#define KP 96    // padded K (halfs); row = 192 B (16B-aligned chunks)

// ---------------- prep: fp32 -> fp16 U matrices + log-space row terms ----------------
__global__ __launch_bounds__(256) void prep_kernel(
    const float* __restrict__ pos1, const float* __restrict__ feat1, const float* __restrict__ w1,
    const float* __restrict__ pos2, const float* __restrict__ feat2, const float* __restrict__ w2,
    f16* __restrict__ U1, f16* __restrict__ U2,
    float* __restrict__ la1, float* __restrict__ la2)
{
    int tid  = threadIdx.x;
    int ridx = blockIdx.x * 16 + (tid >> 4);   // 0..32767
    int c    = tid & 15;
    int side = ridx >> 14;                     // 0: side1, 1: side2
    int idx  = ridx & 16383;                   // b*4096 + row

    const float* feat = side ? feat2 : feat1;
    f16* U   = side ? U2 : U1;
    float fs = side ? -0.5f * L2E : 1.0f;

    float4 v = ((const float4*)feat)[idx * 16 + c];
    *(h4*)(U + (long)idx * KP + 4 + c * 4) =
        h4{(f16)(v.x * fs), (f16)(v.y * fs), (f16)(v.z * fs), (f16)(v.w * fs)};

    if (c == 0) {
        const float* pos = side ? pos2 : pos1;
        const float* w   = side ? w2   : w1;
        float* la = side ? la2 : la1;
        float ps  = side ? 2.0f * L2E : 2.0f;
        float p0 = pos[idx*3+0], p1 = pos[idx*3+1], p2 = pos[idx*3+2];
        la[idx] = __builtin_amdgcn_logf(w[idx]) - 2.0f * L2E * (p0*p0 + p1*p1 + p2*p2);
        *(h4*)(U + (long)idx * KP) = h4{(f16)(p0*ps), (f16)(p1*ps), (f16)(p2*ps), (f16)0.0f};
    } else if (c <= 7) {
        *(h4*)(U + (long)idx * KP + 68 + (c - 1) * 4) =
            h4{(f16)0.0f, (f16)0.0f, (f16)0.0f, (f16)0.0f};
    }
}

// ---------------- main: barrier-free, register-persistent B stripe ------------------
// Block = 4 waves. Wave w owns cols [stripe*256 + w*64, +64) for all rows of its
// 256-row chunk. B frags (3 ksteps x 4 jtiles) + la2 live in registers for the
// whole kernel; A frags are loaded per 16-row tile with 1-tile prefetch.
__global__ __launch_bounds__(256, 4) void varifold_kernel(
    const f16* __restrict__ U1, const f16* __restrict__ U2,
    const float* __restrict__ la1, const float* __restrict__ la2,
    float* __restrict__ pw)
{
    int tid = threadIdx.x, wave = tid >> 6, lane = tid & 63;
    int stripe = blockIdx.x, nchunk = blockIdx.y, b = blockIdx.z;
    int l15 = lane & 15, quad = lane >> 4;

    long colr = (long)b*BN + stripe*256 + wave*64;   // this wave's first col row-index
    long row0 = (long)b*BN + nchunk*256;             // this block's first row

    // --- persistent B fragments + la2 (registers for whole kernel) ---
    v8h bf[3][4];
    float la2v[4];
    #pragma unroll
    for (int j = 0; j < 4; ++j) {
        const f16* r = U2 + (colr + j*16 + l15) * KP + quad*8;
        bf[0][j] = *(const v8h*)(r);
        bf[1][j] = *(const v8h*)(r + 32);
        bf[2][j] = *(const v8h*)(r + 64);
        la2v[j]  = la2[colr + j*16 + l15];
    }

    const f16* Ab = U1 + (row0 + l15) * KP + quad*8;  // A frag base (advance 16 rows/tile)
    v8h afc[3], afn[3];
    afc[0] = *(const v8h*)(Ab);
    afc[1] = *(const v8h*)(Ab + 32);
    afc[2] = *(const v8h*)(Ab + 64);

    float psum = 0.f;
    #pragma unroll 2
    for (int t = 0; t < 16; ++t) {
        // prefetch next tile's A fragments (clamped; last iter re-loads self)
        const f16* An = Ab + (t < 15 ? (t+1) : t) * 16 * KP;
        afn[0] = *(const v8h*)(An);
        afn[1] = *(const v8h*)(An + 32);
        afn[2] = *(const v8h*)(An + 64);

        v4f acc[4];
        #pragma unroll
        for (int j = 0; j < 4; ++j) acc[j] = v4f{0.f, 0.f, 0.f, 0.f};
        #pragma unroll
        for (int k = 0; k < 3; ++k)
            #pragma unroll
            for (int j = 0; j < 4; ++j)
                acc[j] = __builtin_amdgcn_mfma_f32_16x16x32_f16(afc[k], bf[k][j], acc[j], 0, 0, 0);

        // epilogue: C/D layout col=lane&15, row=quad*4+reg
        float4 l1 = *(const float4*)(la1 + row0 + t*16 + quad*4);
        #pragma unroll
        for (int j = 0; j < 4; ++j) {
            v4f d = acc[j];
            psum += __builtin_amdgcn_exp2f(d[0] + l1.x + la2v[j]);
            psum += __builtin_amdgcn_exp2f(d[1] + l1.y + la2v[j]);
            psum += __builtin_amdgcn_exp2f(d[2] + l1.z + la2v[j]);
            psum += __builtin_amdgcn_exp2f(d[3] + l1.w + la2v[j]);
        }

        afc[0] = afn[0]; afc[1] = afn[1]; afc[2] = afn[2];
    }

    // --- wave reduce -> one plain store per wave (no atomics, no LDS) ---
    #pragma unroll
    for (int off = 32; off > 0; off >>= 1) psum += __shfl_down(psum, off);
    if (lane == 0)
        pw[(((long)b*16 + nchunk)*16 + stripe)*4 + wave] = psum;
}

// ---------------- final: reduce 1024 partials per batch -> out[b] -------------------
__global__ __launch_bounds__(256) void reduce_kernel(
    const float* __restrict__ pw, float* __restrict__ out)
{
    __shared__ float sred[4];
    int b = blockIdx.x, tid = threadIdx.x;
    const float* p = pw + (long)b * 1024;
    float v = p[tid] + p[tid + 256] + p[tid + 512] + p[tid + 768];
    #pragma unroll
    for (int off = 32; off > 0; off >>= 1) v += __shfl_down(v, off);
    if ((tid & 63) == 0) sred[tid >> 6] = v;
    __syncthreads();
    if (tid == 0) out[b] = sred[0] + sred[1] + sred[2] + sred[3];
}

extern "C" void kernel_launch(void* const* d_in, const int* in_sizes, int n_in,
                              void* d_out, int out_size, void* d_ws, size_t ws_size,
                              hipStream_t stream) {
    const float* pos1  = (const float*)d_in[0];
    const float* feat1 = (const float*)d_in[1];
    const float* w1    = (const float*)d_in[2];
    const float* pos2  = (const float*)d_in[3];
    const float* feat2 = (const float*)d_in[4];
    const float* w2    = (const float*)d_in[5];
    float* out = (float*)d_out;

    // workspace layout (6,438,912 B)
    char* ws = (char*)d_ws;
    f16*   U1  = (f16*)(ws);                          // 3,145,728
    f16*   U2  = (f16*)(ws + 3145728);                // 3,145,728
    float* la1 = (float*)(ws + 6291456);              // 65,536
    float* la2 = (float*)(ws + 6291456 + 65536);      // 65,536
    float* pw  = (float*)(ws + 6291456 + 131072);     // 4096*4 = 16,384

    prep_kernel<<<2048, 256, 0, stream>>>(pos1, feat1, w1, pos2, feat2, w2, U1, U2, la1, la2);
    dim3 grid(16, 16, 4);  // (stripe, nchunk, b) — stripe fastest: co-dispatched blocks share A rows
    varifold_kernel<<<grid, 256, 0, stream>>>(U1, U2, la1, la2, pw);
    reduce_kernel<<<4, 256, 0, stream>>>(pw, out);
}